// Round 5
// baseline (683.619 us; speedup 1.0000x reference)
//
#include <hip/hip_runtime.h>

#define NN 50000
#define NE 400000

typedef unsigned short u16;
typedef unsigned int   u32;
typedef __bf16 bf16x4 __attribute__((ext_vector_type(4)));
typedef __bf16 bf16x8 __attribute__((ext_vector_type(8)));
typedef float  f32x4  __attribute__((ext_vector_type(4)));

union ABFrag { bf16x8 v; bf16x4 h[2]; };
union BFrag  { uint4 u; bf16x8 v; };

__device__ __forceinline__ u16 f2bfu(float f) {
  u32 u = __builtin_bit_cast(u32, f);
  return (u16)((u + 0x7FFFu + ((u >> 16) & 1u)) >> 16);  // RNE f32->bf16
}
__device__ __forceinline__ float bf2f(u16 u) {
  return __builtin_bit_cast(float, (u32)u << 16);
}

// ---------------- f32 -> bf16 bulk convert (vec4) ----------------
__global__ __launch_bounds__(256) void k_cvt(const float* __restrict__ src,
                                             u16* __restrict__ dst, int n4) {
  int i = blockIdx.x * 256 + threadIdx.x;
  if (i >= n4) return;
  float4 f = ((const float4*)src)[i];
  ushort4 o;
  o.x = f2bfu(f.x); o.y = f2bfu(f.y); o.z = f2bfu(f.z); o.w = f2bfu(f.w);
  ((ushort4*)dst)[i] = o;
}

// ---------------- weight pack (all 4 weights in one launch) ------------------
// pack[((t*256+n)*4+g)*8+j] = W[32t + 4g + (j%4) + 16*(j/4)][n]
__device__ __forceinline__ void pack_one(const float* __restrict__ W,
                                         u16* __restrict__ P, int idx) {
  int k = idx >> 8, n = idx & 255;
  int t = k >> 5, kp = k & 31;
  int g = (kp & 15) >> 2;
  int j = (kp & 3) | ((kp >> 4) << 2);
  P[(((t << 8) + n) << 5) + (g << 3) + j] = f2bfu(W[idx]);
}

__global__ __launch_bounds__(256) void k_pack4(
    const float* __restrict__ Wm, const float* __restrict__ W0,
    const float* __restrict__ W1, const float* __restrict__ W2,
    u16* __restrict__ Pm, u16* __restrict__ P0,
    u16* __restrict__ P1, u16* __restrict__ P2) {
  int idx = blockIdx.x * 256 + threadIdx.x;
  const int S0 = 320 * 256, S1 = S0 + 256 * 256, S2 = S1 + 256 * 256, S3 = S2 + 256 * 256;
  if (idx < S0)      pack_one(Wm, Pm, idx);
  else if (idx < S1) pack_one(W0, P0, idx - S0);
  else if (idx < S2) pack_one(W1, P1, idx - S1);
  else if (idx < S3) pack_one(W2, P2, idx - S2);
}

// ---------------- counting sort of edges by receiver -------------------------
__global__ __launch_bounds__(256) void k_hist(const int* __restrict__ recv,
                                              int* __restrict__ cnt) {
  int i = blockIdx.x * 256 + threadIdx.x;
  if (i < NE) atomicAdd(&cnt[recv[i]], 1);
}

__global__ __launch_bounds__(256) void k_scan1(const int* __restrict__ cnt,
                                               int* __restrict__ loc,
                                               int* __restrict__ bsum) {
  __shared__ int sm[256];
  int t = threadIdx.x, i = blockIdx.x * 256 + t;
  int v = (i < NN) ? cnt[i] : 0;
  sm[t] = v;
  __syncthreads();
  #pragma unroll
  for (int d = 1; d < 256; d <<= 1) {
    int x = sm[t];
    int y = (t >= d) ? sm[t - d] : 0;
    __syncthreads();
    sm[t] = x + y;
    __syncthreads();
  }
  if (i < NN) loc[i] = sm[t] - v;
  if (t == 255) bsum[blockIdx.x] = sm[255];
}

__global__ __launch_bounds__(256) void k_scan2(int* __restrict__ bsum,
                                               int* __restrict__ bpre, int nb) {
  __shared__ int sm[256];
  int t = threadIdx.x;
  int v = (t < nb) ? bsum[t] : 0;
  sm[t] = v;
  __syncthreads();
  #pragma unroll
  for (int d = 1; d < 256; d <<= 1) {
    int x = sm[t];
    int y = (t >= d) ? sm[t - d] : 0;
    __syncthreads();
    sm[t] = x + y;
    __syncthreads();
  }
  if (t < nb) bpre[t] = sm[t] - v;
}

__global__ __launch_bounds__(256) void k_scan3(const int* __restrict__ loc,
                                               const int* __restrict__ bpre,
                                               int* __restrict__ offs,
                                               int* __restrict__ cursor) {
  int i = blockIdx.x * 256 + threadIdx.x;
  if (i < NN) {
    int o = loc[i] + bpre[blockIdx.x];
    offs[i] = o;
    cursor[i] = o;
  }
  if (i == NN - 1) offs[NN] = NE;
}

__global__ __launch_bounds__(256) void k_scatter(
    const int* __restrict__ snd, const int* __restrict__ recv,
    int* __restrict__ cursor, int* __restrict__ s_snd, int* __restrict__ s_eid) {
  int e = blockIdx.x * 256 + threadIdx.x;
  if (e < NE) {
    int p = atomicAdd(&cursor[recv[e]], 1);
    s_snd[p] = snd[e];
    s_eid[p] = e;
  }
}

// ---------------- per-node feature aggregation: X[n] = [Σ s_feat, Σ e_feat] --
__global__ __launch_bounds__(256) void k_aggr(
    const u16* __restrict__ nodes_bf, const float* __restrict__ edges,
    const int* __restrict__ offs, const int* __restrict__ s_snd,
    const int* __restrict__ s_eid, u16* __restrict__ X)
{
  const int wid = blockIdx.x * 4 + (threadIdx.x >> 6);
  const int lane = threadIdx.x & 63;
  const int beg = offs[wid], end = offs[wid + 1];
  float a0 = 0.f, a1 = 0.f, a2 = 0.f, a3 = 0.f, a4 = 0.f;
  for (int j = beg; j < end; ++j) {
    int snd = s_snd[j];
    int eid = s_eid[j];
    ushort4 nv = *(const ushort4*)(nodes_bf + (size_t)snd * 256 + lane * 4);
    float ev = edges[(size_t)eid * 64 + lane];
    a0 += bf2f(nv.x); a1 += bf2f(nv.y); a2 += bf2f(nv.z); a3 += bf2f(nv.w);
    a4 += ev;
  }
  u16* xr = X + (size_t)wid * 320;
  ushort4 o;
  o.x = f2bfu(a0); o.y = f2bfu(a1); o.z = f2bfu(a2); o.w = f2bfu(a3);
  *(ushort4*)(xr + lane * 4) = o;
  xr[256 + lane] = f2bfu(a4);
}

// ---------------- fully fused dense chain ------------------------------------
// h  = LN_a(relu(X@Wm) + nodes)             (h kept bf16 in LDS At, swizzled)
// x += relu(x@W0+b0); x += relu(x@W1+b1)    (residual read back from At)
// out = LN_o(nodes + x + x@W2 + b2)
// B operands read DIRECTLY from global (L2-resident packed weights): no Bt,
// no barriers inside the K-loops.
__global__ __launch_bounds__(256, 3) void k_fused(
    const u16* __restrict__ X, const float* __restrict__ nodes,
    const u16* __restrict__ wm, const u16* __restrict__ w0,
    const u16* __restrict__ w1, const u16* __restrict__ w2,
    const float* __restrict__ b0, const float* __restrict__ b1,
    const float* __restrict__ b2,
    const float* __restrict__ lnAs, const float* __restrict__ lnAb,
    const float* __restrict__ lnOs, const float* __restrict__ lnOb,
    float* __restrict__ out)
{
  __shared__ u16 At[64 * 320];   // XOR-swizzled: byte ^= (row&7)<<4
  __shared__ float red[64][8];
  __shared__ float murs[64][2];

  const int tid = threadIdx.x;
  const int lane = tid & 63, w = tid >> 6;
  const int l16 = lane & 15, g = lane >> 4;
  const int r0 = blockIdx.x * 64;

  char* const atb = (char*)At;
  // swizzled byte address of element (row r, col c) [c in u16 units]
  auto at_addr = [&](int r, int c) -> char* {
    return atb + ((r * 640 + c * 2) ^ ((r & 7) << 4));
  };

  // ---- stage X (bf16, K=320) into swizzled At ----
  #pragma unroll
  for (int it = 0; it < 10; ++it) {
    int c = tid + it * 256;          // 2560 chunks of 16B
    int r = c / 40, seg = c - r * 40;
    int row = r0 + r;
    uint4 v = {0u, 0u, 0u, 0u};
    if (row < NN) v = *(const uint4*)(X + (size_t)row * 320 + seg * 8);
    *(uint4*)(atb + ((r * 640 + seg * 16) ^ ((r & 7) << 4))) = v;
  }

  f32x4 acc[4][4];
  const f32x4 z = {0.f, 0.f, 0.f, 0.f};
  #pragma unroll
  for (int i = 0; i < 4; ++i)
    #pragma unroll
    for (int q = 0; q < 4; ++q) acc[i][q] = z;

  // K-loop over T steps reading B-fragments straight from global (no barriers)
  auto run_gemm = [&](const u16* __restrict__ wp, int T) {
    BFrag bq[4], bn[4];
    #pragma unroll
    for (int q = 0; q < 4; ++q) {
      int n = (w << 6) + (q << 4) + l16;
      bq[q].u = *(const uint4*)(wp + ((size_t)((n << 2) + g) << 3));
    }
    for (int t = 0; t < T; ++t) {
      if (t + 1 < T) {
        #pragma unroll
        for (int q = 0; q < 4; ++q) {
          int n = (w << 6) + (q << 4) + l16;
          bn[q].u = *(const uint4*)(wp + ((size_t)((((t + 1) << 8) + n) << 2) + (size_t)g << 3));
        }
      }
      ABFrag a[4];
      const int kc = (t << 5) + (g << 2);    // u16 col of first half
      #pragma unroll
      for (int mf = 0; mf < 4; ++mf) {
        int m = (mf << 4) + l16;
        a[mf].h[0] = *(const bf16x4*)at_addr(m, kc);
        a[mf].h[1] = *(const bf16x4*)at_addr(m, kc + 16);
      }
      #pragma unroll
      for (int q = 0; q < 4; ++q)
        #pragma unroll
        for (int mf = 0; mf < 4; ++mf)
          acc[mf][q] = __builtin_amdgcn_mfma_f32_16x16x32_bf16(a[mf].v, bq[q].v, acc[mf][q], 0, 0, 0);
      #pragma unroll
      for (int q = 0; q < 4; ++q) bq[q] = bn[q];
    }
  };

  // row/col LN helper: stats of acc (C-layout) -> murs[m] = {mu, rsqrt}
  auto ln_stats = [&]() {
    #pragma unroll
    for (int mf = 0; mf < 4; ++mf) {
      #pragma unroll
      for (int r = 0; r < 4; ++r) {
        float s = 0.f, s2 = 0.f;
        #pragma unroll
        for (int q = 0; q < 4; ++q) {
          float v = acc[mf][q][r];
          s += v; s2 += v * v;
        }
        #pragma unroll
        for (int mk = 1; mk < 16; mk <<= 1) {
          s  += __shfl_xor(s, mk);
          s2 += __shfl_xor(s2, mk);
        }
        if (l16 == 0) {
          int m = (mf << 4) + (g << 2) + r;
          red[m][w * 2]     = s;
          red[m][w * 2 + 1] = s2;
        }
      }
    }
    __syncthreads();              // also: all At reads of prior phase done
    if (tid < 64) {
      float s = 0.f, s2 = 0.f;
      #pragma unroll
      for (int wi = 0; wi < 4; ++wi) { s += red[tid][wi * 2]; s2 += red[tid][wi * 2 + 1]; }
      float mu  = s * (1.f / 256.f);
      float var = s2 * (1.f / 256.f) - mu * mu;
      murs[tid][0] = mu;
      murs[tid][1] = rsqrtf(var + 1e-6f);
    }
    __syncthreads();
  };

  __syncthreads();                // At staged

  // ---- GEMM: X @ Wmsg (K=320) ----
  run_gemm(wm, 10);

  // ---- aggr epilogue: v = relu(acc) + nodes ----
  #pragma unroll
  for (int q = 0; q < 4; ++q) {
    int n = (w << 6) + (q << 4) + l16;
    #pragma unroll
    for (int mf = 0; mf < 4; ++mf) {
      #pragma unroll
      for (int r = 0; r < 4; ++r) {
        int row = r0 + (mf << 4) + (g << 2) + r;
        float nv = (row < NN) ? nodes[(size_t)row * 256 + n] : 0.f;
        acc[mf][q][r] = fmaxf(acc[mf][q][r], 0.f) + nv;
      }
    }
  }
  ln_stats();                     // barrier inside also fences At reads
  // h = LN_a(v) -> bf16 into At (residual + next A operand)
  #pragma unroll
  for (int q = 0; q < 4; ++q) {
    int n = (w << 6) + (q << 4) + l16;
    float scl = lnAs[n], bia = lnAb[n];
    #pragma unroll
    for (int mf = 0; mf < 4; ++mf) {
      #pragma unroll
      for (int r = 0; r < 4; ++r) {
        int m = (mf << 4) + (g << 2) + r;
        float h = (acc[mf][q][r] - murs[m][0]) * murs[m][1] * scl + bia;
        *(u16*)at_addr(m, n) = f2bfu(h);
        acc[mf][q][r] = 0.f;
      }
    }
  }

  // ---- 3 MLP layers; residual lives in At (bf16) ----
  for (int l = 0; l < 3; ++l) {
    const u16* wp = (l == 0) ? w0 : (l == 1) ? w1 : w2;
    __syncthreads();              // At writes visible before K-loop reads
    run_gemm(wp, 8);

    if (l < 2) {
      __syncthreads();            // all At reads done before rewrite
      const float* bp = (l == 0) ? b0 : b1;
      #pragma unroll
      for (int q = 0; q < 4; ++q) {
        int n = (w << 6) + (q << 4) + l16;
        float bn = bp[n];
        #pragma unroll
        for (int mf = 0; mf < 4; ++mf) {
          #pragma unroll
          for (int r = 0; r < 4; ++r) {
            int m = (mf << 4) + (g << 2) + r;
            u16* p = (u16*)at_addr(m, n);
            float xn = bf2f(*p) + fmaxf(acc[mf][q][r] + bn, 0.f);
            *p = f2bfu(xn);       // owner thread RMW
            acc[mf][q][r] = 0.f;
          }
        }
      }
    } else {
      // final: acc = nodes + x + acc + b2   (At only read -> no extra barrier)
      #pragma unroll
      for (int q = 0; q < 4; ++q) {
        int n = (w << 6) + (q << 4) + l16;
        float bn = b2[n];
        #pragma unroll
        for (int mf = 0; mf < 4; ++mf) {
          #pragma unroll
          for (int r = 0; r < 4; ++r) {
            int m = (mf << 4) + (g << 2) + r;
            int row = r0 + m;
            float nv = (row < NN) ? nodes[(size_t)row * 256 + n] : 0.f;
            acc[mf][q][r] = nv + bf2f(*(const u16*)at_addr(m, n)) + acc[mf][q][r] + bn;
          }
        }
      }
    }
  }

  // ---- final LayerNorm over acc ----
  ln_stats();
  #pragma unroll
  for (int q = 0; q < 4; ++q) {
    int n = (w << 6) + (q << 4) + l16;
    float scl = lnOs[n], bia = lnOb[n];
    #pragma unroll
    for (int mf = 0; mf < 4; ++mf) {
      #pragma unroll
      for (int r = 0; r < 4; ++r) {
        int m = (mf << 4) + (g << 2) + r;
        int row = r0 + m;
        if (row < NN)
          out[(size_t)row * 256 + n] =
              (acc[mf][q][r] - murs[m][0]) * murs[m][1] * scl + bia;
      }
    }
  }
}

// ---------------------------------------------------------------------------
extern "C" void kernel_launch(void* const* d_in, const int* in_sizes, int n_in,
                              void* d_out, int out_size, void* d_ws, size_t ws_size,
                              hipStream_t stream)
{
  const float* nodes = (const float*)d_in[0];
  const float* edges = (const float*)d_in[1];
  const int* senders = (const int*)d_in[2];
  const int* receivers = (const int*)d_in[3];
  const float* Wmsg = (const float*)d_in[4];
  const float* W0 = (const float*)d_in[5];
  const float* b0 = (const float*)d_in[6];
  const float* W1 = (const float*)d_in[7];
  const float* b1 = (const float*)d_in[8];
  const float* W2 = (const float*)d_in[9];
  const float* b2 = (const float*)d_in[10];
  const float* lnAs = (const float*)d_in[11];
  const float* lnAb = (const float*)d_in[12];
  const float* lnOs = (const float*)d_in[13];
  const float* lnOb = (const float*)d_in[14];
  float* out = (float*)d_out;
  (void)in_sizes; (void)n_in; (void)out_size; (void)ws_size;

  char* w = (char*)d_ws;
  size_t off = 0;
  auto take = [&](size_t b) { void* p = w + off; off += (b + 511) & ~(size_t)511; return p; };

  u16*   nodes_bf = (u16*)take((size_t)NN * 256 * 2);
  u16*   wmsg_p   = (u16*)take(320 * 256 * 2);
  u16*   w0_p     = (u16*)take(256 * 256 * 2);
  u16*   w1_p     = (u16*)take(256 * 256 * 2);
  u16*   w2_p     = (u16*)take(256 * 256 * 2);
  u16*   X        = (u16*)take((size_t)NN * 320 * 2);
  int*   cnt      = (int*)take((size_t)NN * 4);
  int*   loc      = (int*)take((size_t)NN * 4);
  int*   offs     = (int*)take((size_t)(NN + 1) * 4);
  int*   cursor   = (int*)take((size_t)NN * 4);
  int*   s_snd    = (int*)take((size_t)NE * 4);
  int*   s_eid    = (int*)take((size_t)NE * 4);
  int*   bsum     = (int*)take(256 * 4);
  int*   bpre     = (int*)take(256 * 4);

  const int NB = (NN + 255) / 256;  // 196

  hipMemsetAsync(cnt, 0, (size_t)NN * 4, stream);
  k_cvt<<<(NN * 256 / 4 + 255) / 256, 256, 0, stream>>>(nodes, nodes_bf, NN * 256 / 4);
  k_pack4<<<(320 * 256 + 3 * 256 * 256) / 256, 256, 0, stream>>>(
      Wmsg, W0, W1, W2, wmsg_p, w0_p, w1_p, w2_p);

  k_hist<<<(NE + 255) / 256, 256, 0, stream>>>(receivers, cnt);
  k_scan1<<<NB, 256, 0, stream>>>(cnt, loc, bsum);
  k_scan2<<<1, 256, 0, stream>>>(bsum, bpre, NB);
  k_scan3<<<NB, 256, 0, stream>>>(loc, bpre, offs, cursor);
  k_scatter<<<(NE + 255) / 256, 256, 0, stream>>>(senders, receivers, cursor, s_snd, s_eid);

  k_aggr<<<NN / 4, 256, 0, stream>>>(nodes_bf, edges, offs, s_snd, s_eid, X);

  const int MB = (NN + 63) / 64;
  k_fused<<<MB, 256, 0, stream>>>(X, nodes, wmsg_p, w0_p, w1_p, w2_p,
                                  b0, b1, b2, lnAs, lnAb, lnOs, lnOb, out);
}

// Round 6
// 536.500 us; speedup vs baseline: 1.2742x; 1.2742x over previous
//
#include <hip/hip_runtime.h>

#define NN 50000
#define NE 400000

typedef unsigned short u16;
typedef unsigned int   u32;
typedef __bf16 bf16x4 __attribute__((ext_vector_type(4)));
typedef __bf16 bf16x8 __attribute__((ext_vector_type(8)));
typedef float  f32x4  __attribute__((ext_vector_type(4)));

union ABFrag { bf16x8 v; bf16x4 h[2]; };
union BFrag  { uint4 u; bf16x8 v; };

__device__ __forceinline__ u16 f2bfu(float f) {
  u32 u = __builtin_bit_cast(u32, f);
  return (u16)((u + 0x7FFFu + ((u >> 16) & 1u)) >> 16);  // RNE f32->bf16
}
__device__ __forceinline__ float bf2f(u16 u) {
  return __builtin_bit_cast(float, (u32)u << 16);
}

// ---------------- f32 -> bf16 bulk convert (vec4) ----------------
__global__ __launch_bounds__(256) void k_cvt(const float* __restrict__ src,
                                             u16* __restrict__ dst, int n4) {
  int i = blockIdx.x * 256 + threadIdx.x;
  if (i >= n4) return;
  float4 f = ((const float4*)src)[i];
  ushort4 o;
  o.x = f2bfu(f.x); o.y = f2bfu(f.y); o.z = f2bfu(f.z); o.w = f2bfu(f.w);
  ((ushort4*)dst)[i] = o;
}

// ---------------- weight pack (all 4 weights in one launch) ------------------
// pack[((t*256+n)*4+g)*8+j] = W[32t + 4g + (j%4) + 16*(j/4)][n]
__device__ __forceinline__ void pack_one(const float* __restrict__ W,
                                         u16* __restrict__ P, int idx) {
  int k = idx >> 8, n = idx & 255;
  int t = k >> 5, kp = k & 31;
  int g = (kp & 15) >> 2;
  int j = (kp & 3) | ((kp >> 4) << 2);
  P[(((t << 8) + n) << 5) + (g << 3) + j] = f2bfu(W[idx]);
}

__global__ __launch_bounds__(256) void k_pack4(
    const float* __restrict__ Wm, const float* __restrict__ W0,
    const float* __restrict__ W1, const float* __restrict__ W2,
    u16* __restrict__ Pm, u16* __restrict__ P0,
    u16* __restrict__ P1, u16* __restrict__ P2) {
  int idx = blockIdx.x * 256 + threadIdx.x;
  const int S0 = 320 * 256, S1 = S0 + 256 * 256, S2 = S1 + 256 * 256, S3 = S2 + 256 * 256;
  if (idx < S0)      pack_one(Wm, Pm, idx);
  else if (idx < S1) pack_one(W0, P0, idx - S0);
  else if (idx < S2) pack_one(W1, P1, idx - S1);
  else if (idx < S3) pack_one(W2, P2, idx - S2);
}

// ---------------- counting sort of edges by receiver -------------------------
__global__ __launch_bounds__(256) void k_hist(const int* __restrict__ recv,
                                              int* __restrict__ cnt) {
  int i = blockIdx.x * 256 + threadIdx.x;
  if (i < NE) atomicAdd(&cnt[recv[i]], 1);
}

__global__ __launch_bounds__(256) void k_scan1(const int* __restrict__ cnt,
                                               int* __restrict__ loc,
                                               int* __restrict__ bsum) {
  __shared__ int sm[256];
  int t = threadIdx.x, i = blockIdx.x * 256 + t;
  int v = (i < NN) ? cnt[i] : 0;
  sm[t] = v;
  __syncthreads();
  #pragma unroll
  for (int d = 1; d < 256; d <<= 1) {
    int x = sm[t];
    int y = (t >= d) ? sm[t - d] : 0;
    __syncthreads();
    sm[t] = x + y;
    __syncthreads();
  }
  if (i < NN) loc[i] = sm[t] - v;
  if (t == 255) bsum[blockIdx.x] = sm[255];
}

__global__ __launch_bounds__(256) void k_scan2(int* __restrict__ bsum,
                                               int* __restrict__ bpre, int nb) {
  __shared__ int sm[256];
  int t = threadIdx.x;
  int v = (t < nb) ? bsum[t] : 0;
  sm[t] = v;
  __syncthreads();
  #pragma unroll
  for (int d = 1; d < 256; d <<= 1) {
    int x = sm[t];
    int y = (t >= d) ? sm[t - d] : 0;
    __syncthreads();
    sm[t] = x + y;
    __syncthreads();
  }
  if (t < nb) bpre[t] = sm[t] - v;
}

__global__ __launch_bounds__(256) void k_scan3(const int* __restrict__ loc,
                                               const int* __restrict__ bpre,
                                               int* __restrict__ offs,
                                               int* __restrict__ cursor) {
  int i = blockIdx.x * 256 + threadIdx.x;
  if (i < NN) {
    int o = loc[i] + bpre[blockIdx.x];
    offs[i] = o;
    cursor[i] = o;
  }
  if (i == NN - 1) offs[NN] = NE;
}

__global__ __launch_bounds__(256) void k_scatter(
    const int* __restrict__ snd, const int* __restrict__ recv,
    int* __restrict__ cursor, int* __restrict__ s_snd, int* __restrict__ s_eid) {
  int e = blockIdx.x * 256 + threadIdx.x;
  if (e < NE) {
    int p = atomicAdd(&cursor[recv[e]], 1);
    s_snd[p] = snd[e];
    s_eid[p] = e;
  }
}

// ---------------- per-node feature aggregation: X[n] = [Σ s_feat, Σ e_feat] --
__global__ __launch_bounds__(256) void k_aggr(
    const u16* __restrict__ nodes_bf, const float* __restrict__ edges,
    const int* __restrict__ offs, const int* __restrict__ s_snd,
    const int* __restrict__ s_eid, u16* __restrict__ X)
{
  const int wid = blockIdx.x * 4 + (threadIdx.x >> 6);
  const int lane = threadIdx.x & 63;
  const int beg = offs[wid], end = offs[wid + 1];
  float a0 = 0.f, a1 = 0.f, a2 = 0.f, a3 = 0.f, a4 = 0.f;
  for (int j = beg; j < end; ++j) {
    int snd = s_snd[j];
    int eid = s_eid[j];
    ushort4 nv = *(const ushort4*)(nodes_bf + (size_t)snd * 256 + lane * 4);
    float ev = edges[(size_t)eid * 64 + lane];
    a0 += bf2f(nv.x); a1 += bf2f(nv.y); a2 += bf2f(nv.z); a3 += bf2f(nv.w);
    a4 += ev;
  }
  u16* xr = X + (size_t)wid * 320;
  ushort4 o;
  o.x = f2bfu(a0); o.y = f2bfu(a1); o.z = f2bfu(a2); o.w = f2bfu(a3);
  *(ushort4*)(xr + lane * 4) = o;
  xr[256 + lane] = f2bfu(a4);
}

// ---------------- fully fused dense chain ------------------------------------
// h  = LN_a(relu(X@Wm) + nodes)             (h kept bf16 in LDS At, swizzled)
// x += relu(x@W0+b0); x += relu(x@W1+b1)    (residual read back from At)
// out = LN_o(nodes + x + x@W2 + b2)
// B operands read DIRECTLY from global (L2-resident packed weights): no Bt,
// no barriers inside the K-loops. ONE BFrag live at a time (register budget:
// acc 64 + a 16 + b 8 + addr ~= 130 < 170 @ waves_per_eu=3 -> no spill).
__global__ __launch_bounds__(256, 3) void k_fused(
    const u16* __restrict__ X, const float* __restrict__ nodes,
    const u16* __restrict__ wm, const u16* __restrict__ w0,
    const u16* __restrict__ w1, const u16* __restrict__ w2,
    const float* __restrict__ b0, const float* __restrict__ b1,
    const float* __restrict__ b2,
    const float* __restrict__ lnAs, const float* __restrict__ lnAb,
    const float* __restrict__ lnOs, const float* __restrict__ lnOb,
    float* __restrict__ out)
{
  __shared__ u16 At[64 * 320];   // XOR-swizzled: byte ^= (row&7)<<4
  __shared__ float red[64][8];
  __shared__ float murs[64][2];

  const int tid = threadIdx.x;
  const int lane = tid & 63, w = tid >> 6;
  const int l16 = lane & 15, g = lane >> 4;
  const int r0 = blockIdx.x * 64;

  char* const atb = (char*)At;
  auto at_addr = [&](int r, int c) -> char* {
    return atb + ((r * 640 + c * 2) ^ ((r & 7) << 4));
  };

  // ---- stage X (bf16, K=320) into swizzled At ----
  #pragma unroll
  for (int it = 0; it < 10; ++it) {
    int c = tid + it * 256;          // 2560 chunks of 16B
    int r = c / 40, seg = c - r * 40;
    int row = r0 + r;
    uint4 v = {0u, 0u, 0u, 0u};
    if (row < NN) v = *(const uint4*)(X + (size_t)row * 320 + seg * 8);
    *(uint4*)(atb + ((r * 640 + seg * 16) ^ ((r & 7) << 4))) = v;
  }

  f32x4 acc[4][4];
  const f32x4 z = {0.f, 0.f, 0.f, 0.f};
  #pragma unroll
  for (int i = 0; i < 4; ++i)
    #pragma unroll
    for (int q = 0; q < 4; ++q) acc[i][q] = z;

  // K-loop: B fragments straight from global (L2-hit); minimal live registers.
  auto run_gemm = [&](const u16* __restrict__ wp, int T) {
    #pragma unroll 1
    for (int t = 0; t < T; ++t) {
      ABFrag a[4];
      const int kc = (t << 5) + (g << 2);    // u16 col of first half
      #pragma unroll
      for (int mf = 0; mf < 4; ++mf) {
        int m = (mf << 4) + l16;
        a[mf].h[0] = *(const bf16x4*)at_addr(m, kc);
        a[mf].h[1] = *(const bf16x4*)at_addr(m, kc + 16);
      }
      #pragma unroll
      for (int q = 0; q < 4; ++q) {
        int n = (w << 6) + (q << 4) + l16;
        BFrag b;
        b.u = *(const uint4*)(wp + (size_t)(((t << 8) + n) << 5) + (g << 3));
        #pragma unroll
        for (int mf = 0; mf < 4; ++mf)
          acc[mf][q] = __builtin_amdgcn_mfma_f32_16x16x32_bf16(a[mf].v, b.v, acc[mf][q], 0, 0, 0);
      }
    }
  };

  // stats of acc (C-layout) -> murs[m] = {mu, rsqrt}
  auto ln_stats = [&]() {
    #pragma unroll
    for (int mf = 0; mf < 4; ++mf) {
      #pragma unroll
      for (int r = 0; r < 4; ++r) {
        float s = 0.f, s2 = 0.f;
        #pragma unroll
        for (int q = 0; q < 4; ++q) {
          float v = acc[mf][q][r];
          s += v; s2 += v * v;
        }
        #pragma unroll
        for (int mk = 1; mk < 16; mk <<= 1) {
          s  += __shfl_xor(s, mk);
          s2 += __shfl_xor(s2, mk);
        }
        if (l16 == 0) {
          int m = (mf << 4) + (g << 2) + r;
          red[m][w * 2]     = s;
          red[m][w * 2 + 1] = s2;
        }
      }
    }
    __syncthreads();              // also fences prior At reads
    if (tid < 64) {
      float s = 0.f, s2 = 0.f;
      #pragma unroll
      for (int wi = 0; wi < 4; ++wi) { s += red[tid][wi * 2]; s2 += red[tid][wi * 2 + 1]; }
      float mu  = s * (1.f / 256.f);
      float var = s2 * (1.f / 256.f) - mu * mu;
      murs[tid][0] = mu;
      murs[tid][1] = rsqrtf(var + 1e-6f);
    }
    __syncthreads();
  };

  __syncthreads();                // At staged

  // ---- GEMM: X @ Wmsg (K=320) ----
  run_gemm(wm, 10);

  // ---- aggr epilogue: v = relu(acc) + nodes ----
  #pragma unroll
  for (int q = 0; q < 4; ++q) {
    int n = (w << 6) + (q << 4) + l16;
    #pragma unroll
    for (int mf = 0; mf < 4; ++mf) {
      #pragma unroll
      for (int r = 0; r < 4; ++r) {
        int row = r0 + (mf << 4) + (g << 2) + r;
        float nv = (row < NN) ? nodes[(size_t)row * 256 + n] : 0.f;
        acc[mf][q][r] = fmaxf(acc[mf][q][r], 0.f) + nv;
      }
    }
  }
  ln_stats();
  // h = LN_a(v) -> bf16 into At (residual + next A operand)
  #pragma unroll
  for (int q = 0; q < 4; ++q) {
    int n = (w << 6) + (q << 4) + l16;
    float scl = lnAs[n], bia = lnAb[n];
    #pragma unroll
    for (int mf = 0; mf < 4; ++mf) {
      #pragma unroll
      for (int r = 0; r < 4; ++r) {
        int m = (mf << 4) + (g << 2) + r;
        float h = (acc[mf][q][r] - murs[m][0]) * murs[m][1] * scl + bia;
        *(u16*)at_addr(m, n) = f2bfu(h);
        acc[mf][q][r] = 0.f;
      }
    }
  }

  // ---- 3 MLP layers; residual lives in At (bf16) ----
  for (int l = 0; l < 3; ++l) {
    const u16* wp = (l == 0) ? w0 : (l == 1) ? w1 : w2;
    __syncthreads();              // At writes visible before K-loop reads
    run_gemm(wp, 8);

    if (l < 2) {
      __syncthreads();            // all At reads done before rewrite
      const float* bp = (l == 0) ? b0 : b1;
      #pragma unroll
      for (int q = 0; q < 4; ++q) {
        int n = (w << 6) + (q << 4) + l16;
        float bn = bp[n];
        #pragma unroll
        for (int mf = 0; mf < 4; ++mf) {
          #pragma unroll
          for (int r = 0; r < 4; ++r) {
            int m = (mf << 4) + (g << 2) + r;
            u16* p = (u16*)at_addr(m, n);
            float xn = bf2f(*p) + fmaxf(acc[mf][q][r] + bn, 0.f);
            *p = f2bfu(xn);       // owner thread RMW
            acc[mf][q][r] = 0.f;
          }
        }
      }
    } else {
      // final: acc = nodes + x + acc + b2   (At only read here)
      #pragma unroll
      for (int q = 0; q < 4; ++q) {
        int n = (w << 6) + (q << 4) + l16;
        float bn = b2[n];
        #pragma unroll
        for (int mf = 0; mf < 4; ++mf) {
          #pragma unroll
          for (int r = 0; r < 4; ++r) {
            int m = (mf << 4) + (g << 2) + r;
            int row = r0 + m;
            float nv = (row < NN) ? nodes[(size_t)row * 256 + n] : 0.f;
            acc[mf][q][r] = nv + bf2f(*(const u16*)at_addr(m, n)) + acc[mf][q][r] + bn;
          }
        }
      }
    }
  }

  // ---- final LayerNorm over acc ----
  ln_stats();
  #pragma unroll
  for (int q = 0; q < 4; ++q) {
    int n = (w << 6) + (q << 4) + l16;
    float scl = lnOs[n], bia = lnOb[n];
    #pragma unroll
    for (int mf = 0; mf < 4; ++mf) {
      #pragma unroll
      for (int r = 0; r < 4; ++r) {
        int m = (mf << 4) + (g << 2) + r;
        int row = r0 + m;
        if (row < NN)
          out[(size_t)row * 256 + n] =
              (acc[mf][q][r] - murs[m][0]) * murs[m][1] * scl + bia;
      }
    }
  }
}

// ---------------------------------------------------------------------------
extern "C" void kernel_launch(void* const* d_in, const int* in_sizes, int n_in,
                              void* d_out, int out_size, void* d_ws, size_t ws_size,
                              hipStream_t stream)
{
  const float* nodes = (const float*)d_in[0];
  const float* edges = (const float*)d_in[1];
  const int* senders = (const int*)d_in[2];
  const int* receivers = (const int*)d_in[3];
  const float* Wmsg = (const float*)d_in[4];
  const float* W0 = (const float*)d_in[5];
  const float* b0 = (const float*)d_in[6];
  const float* W1 = (const float*)d_in[7];
  const float* b1 = (const float*)d_in[8];
  const float* W2 = (const float*)d_in[9];
  const float* b2 = (const float*)d_in[10];
  const float* lnAs = (const float*)d_in[11];
  const float* lnAb = (const float*)d_in[12];
  const float* lnOs = (const float*)d_in[13];
  const float* lnOb = (const float*)d_in[14];
  float* out = (float*)d_out;
  (void)in_sizes; (void)n_in; (void)out_size; (void)ws_size;

  char* w = (char*)d_ws;
  size_t off = 0;
  auto take = [&](size_t b) { void* p = w + off; off += (b + 511) & ~(size_t)511; return p; };

  u16*   nodes_bf = (u16*)take((size_t)NN * 256 * 2);
  u16*   wmsg_p   = (u16*)take(320 * 256 * 2);
  u16*   w0_p     = (u16*)take(256 * 256 * 2);
  u16*   w1_p     = (u16*)take(256 * 256 * 2);
  u16*   w2_p     = (u16*)take(256 * 256 * 2);
  u16*   X        = (u16*)take((size_t)NN * 320 * 2);
  int*   cnt      = (int*)take((size_t)NN * 4);
  int*   loc      = (int*)take((size_t)NN * 4);
  int*   offs     = (int*)take((size_t)(NN + 1) * 4);
  int*   cursor   = (int*)take((size_t)NN * 4);
  int*   s_snd    = (int*)take((size_t)NE * 4);
  int*   s_eid    = (int*)take((size_t)NE * 4);
  int*   bsum     = (int*)take(256 * 4);
  int*   bpre     = (int*)take(256 * 4);

  const int NB = (NN + 255) / 256;  // 196

  hipMemsetAsync(cnt, 0, (size_t)NN * 4, stream);
  k_cvt<<<(NN * 256 / 4 + 255) / 256, 256, 0, stream>>>(nodes, nodes_bf, NN * 256 / 4);
  k_pack4<<<(320 * 256 + 3 * 256 * 256) / 256, 256, 0, stream>>>(
      Wmsg, W0, W1, W2, wmsg_p, w0_p, w1_p, w2_p);

  k_hist<<<(NE + 255) / 256, 256, 0, stream>>>(receivers, cnt);
  k_scan1<<<NB, 256, 0, stream>>>(cnt, loc, bsum);
  k_scan2<<<1, 256, 0, stream>>>(bsum, bpre, NB);
  k_scan3<<<NB, 256, 0, stream>>>(loc, bpre, offs, cursor);
  k_scatter<<<(NE + 255) / 256, 256, 0, stream>>>(senders, receivers, cursor, s_snd, s_eid);

  k_aggr<<<NN / 4, 256, 0, stream>>>(nodes_bf, edges, offs, s_snd, s_eid, X);

  const int MB = (NN + 63) / 64;
  k_fused<<<MB, 256, 0, stream>>>(X, nodes, wmsg_p, w0_p, w1_p, w2_p,
                                  b0, b1, b2, lnAs, lnAb, lnOs, lnOb, out);
}

// Round 7
// 352.093 us; speedup vs baseline: 1.9416x; 1.5237x over previous
//
#include <hip/hip_runtime.h>

#define NN 50000
#define NE 400000

typedef unsigned short u16;
typedef unsigned int   u32;
typedef __bf16 bf16x4 __attribute__((ext_vector_type(4)));
typedef __bf16 bf16x8 __attribute__((ext_vector_type(8)));
typedef float  f32x4  __attribute__((ext_vector_type(4)));

union ABFrag { bf16x8 v; bf16x4 h[2]; };
union BFrag  { uint4 u; bf16x8 v; };

__device__ __forceinline__ u16 f2bfu(float f) {
  u32 u = __builtin_bit_cast(u32, f);
  return (u16)((u + 0x7FFFu + ((u >> 16) & 1u)) >> 16);  // RNE f32->bf16
}
__device__ __forceinline__ float bf2f(u16 u) {
  return __builtin_bit_cast(float, (u32)u << 16);
}

// ---------------- f32 -> bf16 bulk convert (vec4) ----------------
__global__ __launch_bounds__(256) void k_cvt(const float* __restrict__ src,
                                             u16* __restrict__ dst, int n4) {
  int i = blockIdx.x * 256 + threadIdx.x;
  if (i >= n4) return;
  float4 f = ((const float4*)src)[i];
  ushort4 o;
  o.x = f2bfu(f.x); o.y = f2bfu(f.y); o.z = f2bfu(f.z); o.w = f2bfu(f.w);
  ((ushort4*)dst)[i] = o;
}

// ---------------- weight pack (all 4 weights in one launch) ------------------
// pack[((t*256+n)*4+g)*8+j] = W[32t + 4g + (j%4) + 16*(j/4)][n]
__device__ __forceinline__ void pack_one(const float* __restrict__ W,
                                         u16* __restrict__ P, int idx) {
  int k = idx >> 8, n = idx & 255;
  int t = k >> 5, kp = k & 31;
  int g = (kp & 15) >> 2;
  int j = (kp & 3) | ((kp >> 4) << 2);
  P[(((t << 8) + n) << 5) + (g << 3) + j] = f2bfu(W[idx]);
}

__global__ __launch_bounds__(256) void k_pack4(
    const float* __restrict__ Wm, const float* __restrict__ W0,
    const float* __restrict__ W1, const float* __restrict__ W2,
    u16* __restrict__ Pm, u16* __restrict__ P0,
    u16* __restrict__ P1, u16* __restrict__ P2) {
  int idx = blockIdx.x * 256 + threadIdx.x;
  const int S0 = 320 * 256, S1 = S0 + 256 * 256, S2 = S1 + 256 * 256, S3 = S2 + 256 * 256;
  if (idx < S0)      pack_one(Wm, Pm, idx);
  else if (idx < S1) pack_one(W0, P0, idx - S0);
  else if (idx < S2) pack_one(W1, P1, idx - S1);
  else if (idx < S3) pack_one(W2, P2, idx - S2);
}

// ---------------- counting sort of edges by receiver -------------------------
__global__ __launch_bounds__(256) void k_hist(const int* __restrict__ recv,
                                              int* __restrict__ cnt) {
  int i = blockIdx.x * 256 + threadIdx.x;
  if (i < NE) atomicAdd(&cnt[recv[i]], 1);
}

__global__ __launch_bounds__(256) void k_scan1(const int* __restrict__ cnt,
                                               int* __restrict__ loc,
                                               int* __restrict__ bsum) {
  __shared__ int sm[256];
  int t = threadIdx.x, i = blockIdx.x * 256 + t;
  int v = (i < NN) ? cnt[i] : 0;
  sm[t] = v;
  __syncthreads();
  #pragma unroll
  for (int d = 1; d < 256; d <<= 1) {
    int x = sm[t];
    int y = (t >= d) ? sm[t - d] : 0;
    __syncthreads();
    sm[t] = x + y;
    __syncthreads();
  }
  if (i < NN) loc[i] = sm[t] - v;
  if (t == 255) bsum[blockIdx.x] = sm[255];
}

__global__ __launch_bounds__(256) void k_scan2(int* __restrict__ bsum,
                                               int* __restrict__ bpre, int nb) {
  __shared__ int sm[256];
  int t = threadIdx.x;
  int v = (t < nb) ? bsum[t] : 0;
  sm[t] = v;
  __syncthreads();
  #pragma unroll
  for (int d = 1; d < 256; d <<= 1) {
    int x = sm[t];
    int y = (t >= d) ? sm[t - d] : 0;
    __syncthreads();
    sm[t] = x + y;
    __syncthreads();
  }
  if (t < nb) bpre[t] = sm[t] - v;
}

__global__ __launch_bounds__(256) void k_scan3(const int* __restrict__ loc,
                                               const int* __restrict__ bpre,
                                               int* __restrict__ offs,
                                               int* __restrict__ cursor) {
  int i = blockIdx.x * 256 + threadIdx.x;
  if (i < NN) {
    int o = loc[i] + bpre[blockIdx.x];
    offs[i] = o;
    cursor[i] = o;
  }
  if (i == NN - 1) offs[NN] = NE;
}

__global__ __launch_bounds__(256) void k_scatter(
    const int* __restrict__ snd, const int* __restrict__ recv,
    int* __restrict__ cursor, int* __restrict__ s_snd, int* __restrict__ s_eid) {
  int e = blockIdx.x * 256 + threadIdx.x;
  if (e < NE) {
    int p = atomicAdd(&cursor[recv[e]], 1);
    s_snd[p] = snd[e];
    s_eid[p] = e;
  }
}

// ---------------- per-node feature aggregation: X[n] = [Σ s_feat, Σ e_feat] --
__global__ __launch_bounds__(256) void k_aggr(
    const u16* __restrict__ nodes_bf, const float* __restrict__ edges,
    const int* __restrict__ offs, const int* __restrict__ s_snd,
    const int* __restrict__ s_eid, u16* __restrict__ X)
{
  const int wid = blockIdx.x * 4 + (threadIdx.x >> 6);
  const int lane = threadIdx.x & 63;
  const int beg = offs[wid], end = offs[wid + 1];
  float a0 = 0.f, a1 = 0.f, a2 = 0.f, a3 = 0.f, a4 = 0.f;
  for (int j = beg; j < end; ++j) {
    int snd = s_snd[j];
    int eid = s_eid[j];
    ushort4 nv = *(const ushort4*)(nodes_bf + (size_t)snd * 256 + lane * 4);
    float ev = edges[(size_t)eid * 64 + lane];
    a0 += bf2f(nv.x); a1 += bf2f(nv.y); a2 += bf2f(nv.z); a3 += bf2f(nv.w);
    a4 += ev;
  }
  u16* xr = X + (size_t)wid * 320;
  ushort4 o;
  o.x = f2bfu(a0); o.y = f2bfu(a1); o.z = f2bfu(a2); o.w = f2bfu(a3);
  *(ushort4*)(xr + lane * 4) = o;
  xr[256 + lane] = f2bfu(a4);
}

// ---------------- fully fused dense chain ------------------------------------
// 512 threads = 8 waves: wr = row-half (32 rows), wc = col-quarter (64 cols).
// acc[2][4] = 32 VGPRs/thread. Bt LDS-staged per K=64 step with register
// prefetch of the next step issued under the current MFMA phase.
// amdgpu_waves_per_eu(4,4) pins exactly 2 blocks/CU -> no occupancy-chasing
// register spills (the round 3-6 killer).
__global__ __launch_bounds__(512)
__attribute__((amdgpu_waves_per_eu(4, 4)))
void k_fused(
    const u16* __restrict__ X, const float* __restrict__ nodes,
    const u16* __restrict__ wm, const u16* __restrict__ w0,
    const u16* __restrict__ w1, const u16* __restrict__ w2,
    const float* __restrict__ b0, const float* __restrict__ b1,
    const float* __restrict__ b2,
    const float* __restrict__ lnAs, const float* __restrict__ lnAb,
    const float* __restrict__ lnOs, const float* __restrict__ lnOb,
    float* __restrict__ out)
{
  __shared__ u16 At[64 * 320];     // XOR-swizzled: byte ^= (row&7)<<4
  __shared__ u16 Bt[16384];        // K=64 step: [sub2][g4][n256][j8], ^ (g<<4) u16-swz
  __shared__ float red[64][8];
  __shared__ float murs[64][2];

  const int tid = threadIdx.x;
  const int lane = tid & 63;
  const int w8 = tid >> 6;             // 0..7
  const int wr = w8 >> 2, wc = w8 & 3; // row-half, col-quarter
  const int l16 = lane & 15, g = lane >> 4;
  const int r0 = blockIdx.x * 64;

  char* const atb = (char*)At;
  auto at_addr = [&](int r, int c) -> char* {        // c in u16 units
    return atb + ((r * 640 + c * 2) ^ ((r & 7) << 4));
  };

  // ---- stage X (bf16, K=320) into swizzled At ----
  #pragma unroll
  for (int it = 0; it < 5; ++it) {
    int c = tid + it * 512;            // 2560 chunks of 16B
    int r = c / 40, seg = c - r * 40;
    int row = r0 + r;
    uint4 v = {0u, 0u, 0u, 0u};
    if (row < NN) v = *(const uint4*)(X + (size_t)row * 320 + seg * 8);
    *(uint4*)(atb + ((r * 640 + seg * 16) ^ ((r & 7) << 4))) = v;
  }

  f32x4 acc[2][4];
  const f32x4 z = {0.f, 0.f, 0.f, 0.f};
  #pragma unroll
  for (int i = 0; i < 2; ++i)
    #pragma unroll
    for (int q = 0; q < 4; ++q) acc[i][q] = z;

  // Bt u16-index for chunk c (c = sub*1024 + n*4 + gg), XOR gg into bank bits
  auto wrBt = [&](int c, uint4 v) {
    int idx = (((c >> 10) << 13) + ((c & 3) << 11) + (((c & 1023) >> 2) << 3))
              ^ ((c & 3) << 4);
    *(uint4*)&Bt[idx] = v;
  };

  // one layer: T K=64-steps; B tile prefetched one step ahead into registers
  auto run_layer = [&](const u16* __restrict__ wp, int T) {
    const u16* pbase = wp + ((size_t)tid << 3);
    uint4 p0 = *(const uint4*)(pbase);
    uint4 p1 = *(const uint4*)(pbase + 4096);
    uint4 p2 = *(const uint4*)(pbase + 8192);
    uint4 p3 = *(const uint4*)(pbase + 12288);
    #pragma unroll 1
    for (int t = 0; t < T; ++t) {
      __syncthreads();                 // Bt free (prev MFMA done); At visible
      wrBt(tid,        p0);
      wrBt(tid + 512,  p1);
      wrBt(tid + 1024, p2);
      wrBt(tid + 1536, p3);
      if (t + 1 < T) {                 // prefetch next step under this MFMA
        const u16* nb = pbase + ((size_t)(t + 1) << 14);
        p0 = *(const uint4*)(nb);
        p1 = *(const uint4*)(nb + 4096);
        p2 = *(const uint4*)(nb + 8192);
        p3 = *(const uint4*)(nb + 12288);
      }
      __syncthreads();                 // Bt visible
      #pragma unroll
      for (int kk = 0; kk < 2; ++kk) {
        ABFrag a[2];
        const int kc = ((t * 2 + kk) << 5) + (g << 2);
        #pragma unroll
        for (int mf = 0; mf < 2; ++mf) {
          int m = wr * 32 + mf * 16 + l16;
          a[mf].h[0] = *(const bf16x4*)at_addr(m, kc);
          a[mf].h[1] = *(const bf16x4*)at_addr(m, kc + 16);
        }
        #pragma unroll
        for (int q = 0; q < 4; ++q) {
          int n = (wc << 6) + (q << 4) + l16;
          BFrag b;
          b.u = *(const uint4*)&Bt[((kk << 13) + (g << 11) + (n << 3)) ^ (g << 4)];
          acc[0][q] = __builtin_amdgcn_mfma_f32_16x16x32_bf16(a[0].v, b.v, acc[0][q], 0, 0, 0);
          acc[1][q] = __builtin_amdgcn_mfma_f32_16x16x32_bf16(a[1].v, b.v, acc[1][q], 0, 0, 0);
        }
      }
    }
  };

  // LN stats of acc rows (C-layout) -> murs[m] = {mu, rsqrt}
  auto ln_stats = [&]() {
    #pragma unroll
    for (int mf = 0; mf < 2; ++mf) {
      #pragma unroll
      for (int r = 0; r < 4; ++r) {
        float s = 0.f, s2 = 0.f;
        #pragma unroll
        for (int q = 0; q < 4; ++q) {
          float v = acc[mf][q][r];
          s += v; s2 += v * v;
        }
        #pragma unroll
        for (int mk = 1; mk < 16; mk <<= 1) {
          s  += __shfl_xor(s, mk);
          s2 += __shfl_xor(s2, mk);
        }
        if (l16 == 0) {
          int m = wr * 32 + mf * 16 + g * 4 + r;
          red[m][wc * 2]     = s;
          red[m][wc * 2 + 1] = s2;
        }
      }
    }
    __syncthreads();
    if (tid < 64) {
      float s  = red[tid][0] + red[tid][2] + red[tid][4] + red[tid][6];
      float s2 = red[tid][1] + red[tid][3] + red[tid][5] + red[tid][7];
      float mu  = s * (1.f / 256.f);
      float var = s2 * (1.f / 256.f) - mu * mu;
      murs[tid][0] = mu;
      murs[tid][1] = rsqrtf(var + 1e-6f);
    }
    __syncthreads();
  };

  // ---- GEMM: X @ Wmsg (K=320, 5 steps) ----
  run_layer(wm, 5);

  // ---- aggr epilogue: v = relu(acc) + nodes ----
  #pragma unroll
  for (int q = 0; q < 4; ++q) {
    int n = (wc << 6) + (q << 4) + l16;
    #pragma unroll
    for (int mf = 0; mf < 2; ++mf) {
      #pragma unroll
      for (int r = 0; r < 4; ++r) {
        int row = r0 + wr * 32 + mf * 16 + g * 4 + r;
        float nv = (row < NN) ? nodes[(size_t)row * 256 + n] : 0.f;
        acc[mf][q][r] = fmaxf(acc[mf][q][r], 0.f) + nv;
      }
    }
  }
  ln_stats();
  // h = LN_a(v) -> bf16 into At (residual + next A operand)
  #pragma unroll
  for (int q = 0; q < 4; ++q) {
    int n = (wc << 6) + (q << 4) + l16;
    float scl = lnAs[n], bia = lnAb[n];
    #pragma unroll
    for (int mf = 0; mf < 2; ++mf) {
      #pragma unroll
      for (int r = 0; r < 4; ++r) {
        int m = wr * 32 + mf * 16 + g * 4 + r;
        float h = (acc[mf][q][r] - murs[m][0]) * murs[m][1] * scl + bia;
        *(u16*)at_addr(m, n) = f2bfu(h);
        acc[mf][q][r] = 0.f;
      }
    }
  }

  // ---- 3 MLP layers; residual lives in At (bf16) ----
  #pragma unroll 1
  for (int l = 0; l < 3; ++l) {
    const u16* wp = (l == 0) ? w0 : (l == 1) ? w1 : w2;
    run_layer(wp, 4);

    if (l < 2) {
      __syncthreads();                 // all At MFMA reads done before RMW
      const float* bp = (l == 0) ? b0 : b1;
      #pragma unroll
      for (int q = 0; q < 4; ++q) {
        int n = (wc << 6) + (q << 4) + l16;
        float bn = bp[n];
        #pragma unroll
        for (int mf = 0; mf < 2; ++mf) {
          #pragma unroll
          for (int r = 0; r < 4; ++r) {
            int m = wr * 32 + mf * 16 + g * 4 + r;
            u16* p = (u16*)at_addr(m, n);
            float xn = bf2f(*p) + fmaxf(acc[mf][q][r] + bn, 0.f);
            *p = f2bfu(xn);            // owner-thread RMW (disjoint across waves)
            acc[mf][q][r] = 0.f;
          }
        }
      }
    } else {
      // final: acc = nodes + x + acc + b2  (At read-only here)
      #pragma unroll
      for (int q = 0; q < 4; ++q) {
        int n = (wc << 6) + (q << 4) + l16;
        float bn = b2[n];
        #pragma unroll
        for (int mf = 0; mf < 2; ++mf) {
          #pragma unroll
          for (int r = 0; r < 4; ++r) {
            int m = wr * 32 + mf * 16 + g * 4 + r;
            int row = r0 + m;
            float nv = (row < NN) ? nodes[(size_t)row * 256 + n] : 0.f;
            acc[mf][q][r] = nv + bf2f(*(const u16*)at_addr(m, n)) + acc[mf][q][r] + bn;
          }
        }
      }
    }
  }

  // ---- final LayerNorm ----
  ln_stats();
  #pragma unroll
  for (int q = 0; q < 4; ++q) {
    int n = (wc << 6) + (q << 4) + l16;
    float scl = lnOs[n], bia = lnOb[n];
    #pragma unroll
    for (int mf = 0; mf < 2; ++mf) {
      #pragma unroll
      for (int r = 0; r < 4; ++r) {
        int m = wr * 32 + mf * 16 + g * 4 + r;
        int row = r0 + m;
        if (row < NN)
          out[(size_t)row * 256 + n] =
              (acc[mf][q][r] - murs[m][0]) * murs[m][1] * scl + bia;
      }
    }
  }
}

// ---------------------------------------------------------------------------
extern "C" void kernel_launch(void* const* d_in, const int* in_sizes, int n_in,
                              void* d_out, int out_size, void* d_ws, size_t ws_size,
                              hipStream_t stream)
{
  const float* nodes = (const float*)d_in[0];
  const float* edges = (const float*)d_in[1];
  const int* senders = (const int*)d_in[2];
  const int* receivers = (const int*)d_in[3];
  const float* Wmsg = (const float*)d_in[4];
  const float* W0 = (const float*)d_in[5];
  const float* b0 = (const float*)d_in[6];
  const float* W1 = (const float*)d_in[7];
  const float* b1 = (const float*)d_in[8];
  const float* W2 = (const float*)d_in[9];
  const float* b2 = (const float*)d_in[10];
  const float* lnAs = (const float*)d_in[11];
  const float* lnAb = (const float*)d_in[12];
  const float* lnOs = (const float*)d_in[13];
  const float* lnOb = (const float*)d_in[14];
  float* out = (float*)d_out;
  (void)in_sizes; (void)n_in; (void)out_size; (void)ws_size;

  char* w = (char*)d_ws;
  size_t off = 0;
  auto take = [&](size_t b) { void* p = w + off; off += (b + 511) & ~(size_t)511; return p; };

  u16*   nodes_bf = (u16*)take((size_t)NN * 256 * 2);
  u16*   wmsg_p   = (u16*)take(320 * 256 * 2);
  u16*   w0_p     = (u16*)take(256 * 256 * 2);
  u16*   w1_p     = (u16*)take(256 * 256 * 2);
  u16*   w2_p     = (u16*)take(256 * 256 * 2);
  u16*   X        = (u16*)take((size_t)NN * 320 * 2);
  int*   cnt      = (int*)take((size_t)NN * 4);
  int*   loc      = (int*)take((size_t)NN * 4);
  int*   offs     = (int*)take((size_t)(NN + 1) * 4);
  int*   cursor   = (int*)take((size_t)NN * 4);
  int*   s_snd    = (int*)take((size_t)NE * 4);
  int*   s_eid    = (int*)take((size_t)NE * 4);
  int*   bsum     = (int*)take(256 * 4);
  int*   bpre     = (int*)take(256 * 4);

  const int NB = (NN + 255) / 256;  // 196

  hipMemsetAsync(cnt, 0, (size_t)NN * 4, stream);
  k_cvt<<<(NN * 256 / 4 + 255) / 256, 256, 0, stream>>>(nodes, nodes_bf, NN * 256 / 4);
  k_pack4<<<(320 * 256 + 3 * 256 * 256) / 256, 256, 0, stream>>>(
      Wmsg, W0, W1, W2, wmsg_p, w0_p, w1_p, w2_p);

  k_hist<<<(NE + 255) / 256, 256, 0, stream>>>(receivers, cnt);
  k_scan1<<<NB, 256, 0, stream>>>(cnt, loc, bsum);
  k_scan2<<<1, 256, 0, stream>>>(bsum, bpre, NB);
  k_scan3<<<NB, 256, 0, stream>>>(loc, bpre, offs, cursor);
  k_scatter<<<(NE + 255) / 256, 256, 0, stream>>>(senders, receivers, cursor, s_snd, s_eid);

  k_aggr<<<NN / 4, 256, 0, stream>>>(nodes_bf, edges, offs, s_snd, s_eid, X);

  const int MB = (NN + 63) / 64;    // 782
  k_fused<<<MB, 512, 0, stream>>>(X, nodes, wmsg_p, w0_p, w1_p, w2_p,
                                  b0, b1, b2, lnAs, lnAb, lnOs, lnOb, out);
}

// Round 8
// 233.230 us; speedup vs baseline: 2.9311x; 1.5096x over previous
//
#include <hip/hip_runtime.h>

#define NN 50000
#define NE 400000

typedef unsigned short u16;
typedef unsigned int   u32;
typedef __bf16 bf16x4 __attribute__((ext_vector_type(4)));
typedef __bf16 bf16x8 __attribute__((ext_vector_type(8)));
typedef float  f32x4  __attribute__((ext_vector_type(4)));

union ABFrag { bf16x8 v; bf16x4 h[2]; };
union BFrag  { uint4 u; bf16x8 v; };

__device__ __forceinline__ u16 f2bfu(float f) {
  u32 u = __builtin_bit_cast(u32, f);
  return (u16)((u + 0x7FFFu + ((u >> 16) & 1u)) >> 16);  // RNE f32->bf16
}
__device__ __forceinline__ float bf2f(u16 u) {
  return __builtin_bit_cast(float, (u32)u << 16);
}

// ---------------- f32 -> bf16 bulk convert (vec4) ----------------
__global__ __launch_bounds__(256) void k_cvt(const float* __restrict__ src,
                                             u16* __restrict__ dst, int n4) {
  int i = blockIdx.x * 256 + threadIdx.x;
  if (i >= n4) return;
  float4 f = ((const float4*)src)[i];
  ushort4 o;
  o.x = f2bfu(f.x); o.y = f2bfu(f.y); o.z = f2bfu(f.z); o.w = f2bfu(f.w);
  ((ushort4*)dst)[i] = o;
}

// ---------------- weight pack (all 4 weights in one launch) ------------------
// pack[((t*256+n)*4+g)*8+j] = W[32t + 4g + (j%4) + 16*(j/4)][n]
__device__ __forceinline__ void pack_one(const float* __restrict__ W,
                                         u16* __restrict__ P, int idx) {
  int k = idx >> 8, n = idx & 255;
  int t = k >> 5, kp = k & 31;
  int g = (kp & 15) >> 2;
  int j = (kp & 3) | ((kp >> 4) << 2);
  P[(((t << 8) + n) << 5) + (g << 3) + j] = f2bfu(W[idx]);
}

__global__ __launch_bounds__(256) void k_pack4(
    const float* __restrict__ Wm, const float* __restrict__ W0,
    const float* __restrict__ W1, const float* __restrict__ W2,
    u16* __restrict__ Pm, u16* __restrict__ P0,
    u16* __restrict__ P1, u16* __restrict__ P2) {
  int idx = blockIdx.x * 256 + threadIdx.x;
  const int S0 = 320 * 256, S1 = S0 + 256 * 256, S2 = S1 + 256 * 256, S3 = S2 + 256 * 256;
  if (idx < S0)      pack_one(Wm, Pm, idx);
  else if (idx < S1) pack_one(W0, P0, idx - S0);
  else if (idx < S2) pack_one(W1, P1, idx - S1);
  else if (idx < S3) pack_one(W2, P2, idx - S2);
}

// ---------------- counting sort of edges by receiver -------------------------
__global__ __launch_bounds__(256) void k_hist(const int* __restrict__ recv,
                                              int* __restrict__ cnt) {
  int i = blockIdx.x * 256 + threadIdx.x;
  if (i < NE) atomicAdd(&cnt[recv[i]], 1);
}

__global__ __launch_bounds__(256) void k_scan1(const int* __restrict__ cnt,
                                               int* __restrict__ loc,
                                               int* __restrict__ bsum) {
  __shared__ int sm[256];
  int t = threadIdx.x, i = blockIdx.x * 256 + t;
  int v = (i < NN) ? cnt[i] : 0;
  sm[t] = v;
  __syncthreads();
  #pragma unroll
  for (int d = 1; d < 256; d <<= 1) {
    int x = sm[t];
    int y = (t >= d) ? sm[t - d] : 0;
    __syncthreads();
    sm[t] = x + y;
    __syncthreads();
  }
  if (i < NN) loc[i] = sm[t] - v;
  if (t == 255) bsum[blockIdx.x] = sm[255];
}

__global__ __launch_bounds__(256) void k_scan2(int* __restrict__ bsum,
                                               int* __restrict__ bpre, int nb) {
  __shared__ int sm[256];
  int t = threadIdx.x;
  int v = (t < nb) ? bsum[t] : 0;
  sm[t] = v;
  __syncthreads();
  #pragma unroll
  for (int d = 1; d < 256; d <<= 1) {
    int x = sm[t];
    int y = (t >= d) ? sm[t - d] : 0;
    __syncthreads();
    sm[t] = x + y;
    __syncthreads();
  }
  if (t < nb) bpre[t] = sm[t] - v;
}

__global__ __launch_bounds__(256) void k_scan3(const int* __restrict__ loc,
                                               const int* __restrict__ bpre,
                                               int* __restrict__ offs,
                                               int* __restrict__ cursor) {
  int i = blockIdx.x * 256 + threadIdx.x;
  if (i < NN) {
    int o = loc[i] + bpre[blockIdx.x];
    offs[i] = o;
    cursor[i] = o;
  }
  if (i == NN - 1) offs[NN] = NE;
}

__global__ __launch_bounds__(256) void k_scatter(
    const int* __restrict__ snd, const int* __restrict__ recv,
    int* __restrict__ cursor, int* __restrict__ s_snd, int* __restrict__ s_eid) {
  int e = blockIdx.x * 256 + threadIdx.x;
  if (e < NE) {
    int p = atomicAdd(&cursor[recv[e]], 1);
    s_snd[p] = snd[e];
    s_eid[p] = e;
  }
}

// ---------------- per-node feature aggregation: X[n] = [Σ s_feat, Σ e_feat] --
__global__ __launch_bounds__(256) void k_aggr(
    const u16* __restrict__ nodes_bf, const float* __restrict__ edges,
    const int* __restrict__ offs, const int* __restrict__ s_snd,
    const int* __restrict__ s_eid, u16* __restrict__ X)
{
  const int wid = blockIdx.x * 4 + (threadIdx.x >> 6);
  const int lane = threadIdx.x & 63;
  const int beg = offs[wid], end = offs[wid + 1];
  float a0 = 0.f, a1 = 0.f, a2 = 0.f, a3 = 0.f, a4 = 0.f;
  int j = beg;
  for (; j + 1 < end; j += 2) {      // two independent gathers in flight
    int sA = s_snd[j],     eA = s_eid[j];
    int sB = s_snd[j + 1], eB = s_eid[j + 1];
    ushort4 nA = *(const ushort4*)(nodes_bf + (size_t)sA * 256 + lane * 4);
    ushort4 nB = *(const ushort4*)(nodes_bf + (size_t)sB * 256 + lane * 4);
    float evA = edges[(size_t)eA * 64 + lane];
    float evB = edges[(size_t)eB * 64 + lane];
    a0 += bf2f(nA.x) + bf2f(nB.x); a1 += bf2f(nA.y) + bf2f(nB.y);
    a2 += bf2f(nA.z) + bf2f(nB.z); a3 += bf2f(nA.w) + bf2f(nB.w);
    a4 += evA + evB;
  }
  if (j < end) {
    int sA = s_snd[j], eA = s_eid[j];
    ushort4 nA = *(const ushort4*)(nodes_bf + (size_t)sA * 256 + lane * 4);
    a0 += bf2f(nA.x); a1 += bf2f(nA.y); a2 += bf2f(nA.z); a3 += bf2f(nA.w);
    a4 += edges[(size_t)eA * 64 + lane];
  }
  u16* xr = X + (size_t)wid * 320;
  ushort4 o;
  o.x = f2bfu(a0); o.y = f2bfu(a1); o.z = f2bfu(a2); o.w = f2bfu(a3);
  *(ushort4*)(xr + lane * 4) = o;
  xr[256 + lane] = f2bfu(a4);
}

// ---------------- fully fused dense chain ------------------------------------
// 1024 threads = 16 waves: wr = row-quarter (16 rows), wc = col-quarter (64
// cols). acc[4] = 16 VGPRs/thread; total live ~45 < 64 -> fits the allocator's
// 64-reg occupancy target with NO spill (rounds 3-7 killer). LDS 76.3 KB ->
// 2 blocks/CU = 32 waves/CU. All helpers are macros (no lambda outlining).

#define AT_ADDR(r, c) (atb + ((((r) * 640) + ((c) * 2)) ^ (((r) & 7) << 4)))

#define WRBT(c, v) do { int _c = (c); \
  int _i = (((_c >> 10) << 13) + ((_c & 3) << 11) + (((_c & 1023) >> 2) << 3)) ^ ((_c & 3) << 4); \
  *(uint4*)&Bt[_i] = (v); } while (0)

#define MFMA_STEP(t) \
  _Pragma("unroll") \
  for (int kk = 0; kk < 2; ++kk) { \
    ABFrag a; \
    const int kc = (((t) * 2 + kk) << 5) + (g << 2); \
    const int m = wr16 + l16; \
    a.h[0] = *(const bf16x4*)AT_ADDR(m, kc); \
    a.h[1] = *(const bf16x4*)AT_ADDR(m, kc + 16); \
    _Pragma("unroll") \
    for (int q = 0; q < 4; ++q) { \
      BFrag b; \
      b.u = *(const uint4*)&Bt[((kk << 13) + (g << 11) + ((wcn + (q << 4) + l16) << 3)) ^ (g << 4)]; \
      acc[q] = __builtin_amdgcn_mfma_f32_16x16x32_bf16(a.v, b.v, acc[q], 0, 0, 0); \
    } \
  }

#define RUN_LAYER(wp, T) do { \
  const u16* pb = (wp) + ((size_t)tid << 3); \
  uint4 p0 = *(const uint4*)(pb); \
  uint4 p1 = *(const uint4*)(pb + 8192); \
  _Pragma("unroll 1") \
  for (int t = 0; t < (T); ++t) { \
    __syncthreads(); \
    WRBT(tid, p0); WRBT(tid + 1024, p1); \
    if (t + 1 < (T)) { \
      const u16* nb = pb + ((size_t)(t + 1) << 14); \
      p0 = *(const uint4*)nb; p1 = *(const uint4*)(nb + 8192); \
    } \
    __syncthreads(); \
    MFMA_STEP(t) \
  } \
} while (0)

#define LN_STATS() do { \
  _Pragma("unroll") \
  for (int r = 0; r < 4; ++r) { \
    float s  = acc[0][r] + acc[1][r] + acc[2][r] + acc[3][r]; \
    float s2 = acc[0][r]*acc[0][r] + acc[1][r]*acc[1][r] + acc[2][r]*acc[2][r] + acc[3][r]*acc[3][r]; \
    s  += __shfl_xor(s, 1);  s  += __shfl_xor(s, 2);  s  += __shfl_xor(s, 4);  s  += __shfl_xor(s, 8); \
    s2 += __shfl_xor(s2, 1); s2 += __shfl_xor(s2, 2); s2 += __shfl_xor(s2, 4); s2 += __shfl_xor(s2, 8); \
    if (l16 == 0) { int m = wr16 + g4 + r; red[m][wc2] = s; red[m][wc2 + 1] = s2; } \
  } \
  __syncthreads(); \
  if (tid < 64) { \
    float s  = red[tid][0] + red[tid][2] + red[tid][4] + red[tid][6]; \
    float s2 = red[tid][1] + red[tid][3] + red[tid][5] + red[tid][7]; \
    float mu  = s * (1.f / 256.f); \
    float var = s2 * (1.f / 256.f) - mu * mu; \
    murs[tid][0] = mu; murs[tid][1] = rsqrtf(var + 1e-6f); \
  } \
  __syncthreads(); \
} while (0)

__global__ __launch_bounds__(1024)
void k_fused(
    const u16* __restrict__ X, const float* __restrict__ nodes,
    const u16* __restrict__ wm, const u16* __restrict__ w0,
    const u16* __restrict__ w1, const u16* __restrict__ w2,
    const float* __restrict__ b0, const float* __restrict__ b1,
    const float* __restrict__ b2,
    const float* __restrict__ lnAs, const float* __restrict__ lnAb,
    const float* __restrict__ lnOs, const float* __restrict__ lnOb,
    float* __restrict__ out)
{
  __shared__ u16 At[64 * 320];     // XOR-swizzled: byte ^= (row&7)<<4
  __shared__ u16 Bt[16384];        // K=64 step: [kk][g][n][j] ^ (g<<4) u16-swz
  __shared__ float red[64][8];
  __shared__ float murs[64][2];

  const int tid = threadIdx.x;
  const int lane = tid & 63;
  const int w16 = tid >> 6;              // 0..15
  const int wr16 = (w16 >> 2) << 4;      // row base within tile (0,16,32,48)
  const int wcn = (w16 & 3) << 6;        // col base (0,64,128,192)
  const int wc2 = (w16 & 3) << 1;
  const int l16 = lane & 15, g = lane >> 4, g4 = g << 2;
  const int r0 = blockIdx.x * 64;

  char* const atb = (char*)At;

  // ---- stage X (bf16, K=320) into swizzled At ----
  #pragma unroll
  for (int it = 0; it < 3; ++it) {
    int c = tid + it * 1024;             // 2560 chunks of 16B
    if (c < 2560) {
      int r = c / 40, seg = c - r * 40;
      int row = r0 + r;
      uint4 v = {0u, 0u, 0u, 0u};
      if (row < NN) v = *(const uint4*)(X + (size_t)row * 320 + seg * 8);
      *(uint4*)(atb + ((r * 640 + seg * 16) ^ ((r & 7) << 4))) = v;
    }
  }

  f32x4 acc[4];
  const f32x4 z = {0.f, 0.f, 0.f, 0.f};
  #pragma unroll
  for (int q = 0; q < 4; ++q) acc[q] = z;

  // ---- GEMM: X @ Wmsg (K=320, 5 steps of 64) ----
  RUN_LAYER(wm, 5);

  // ---- aggr epilogue: v = relu(acc) + nodes ----
  #pragma unroll
  for (int q = 0; q < 4; ++q) {
    int n = wcn + (q << 4) + l16;
    #pragma unroll
    for (int r = 0; r < 4; ++r) {
      int row = r0 + wr16 + g4 + r;
      float nv = (row < NN) ? nodes[(size_t)row * 256 + n] : 0.f;
      acc[q][r] = fmaxf(acc[q][r], 0.f) + nv;
    }
  }
  LN_STATS();                            // barrier inside also fences At reads
  // h = LN_a(v) -> bf16 into At (residual + next A operand)
  #pragma unroll
  for (int q = 0; q < 4; ++q) {
    int n = wcn + (q << 4) + l16;
    float scl = lnAs[n], bia = lnAb[n];
    #pragma unroll
    for (int r = 0; r < 4; ++r) {
      int m = wr16 + g4 + r;
      float h = (acc[q][r] - murs[m][0]) * murs[m][1] * scl + bia;
      *(u16*)AT_ADDR(m, n) = f2bfu(h);
      acc[q][r] = 0.f;
    }
  }

  // ---- 3 MLP layers; residual lives in At (bf16) ----
  #pragma unroll 1
  for (int l = 0; l < 3; ++l) {
    const u16* wp = (l == 0) ? w0 : (l == 1) ? w1 : w2;
    RUN_LAYER(wp, 4);
    __syncthreads();                     // all At MFMA reads done

    if (l < 2) {
      const float* bp = (l == 0) ? b0 : b1;
      #pragma unroll
      for (int q = 0; q < 4; ++q) {
        int n = wcn + (q << 4) + l16;
        float bn = bp[n];
        #pragma unroll
        for (int r = 0; r < 4; ++r) {
          int m = wr16 + g4 + r;
          u16* p = (u16*)AT_ADDR(m, n);
          float xn = bf2f(*p) + fmaxf(acc[q][r] + bn, 0.f);
          *p = f2bfu(xn);                // owner-thread RMW (disjoint)
          acc[q][r] = 0.f;
        }
      }
    } else {
      // final: acc = nodes + x + acc + b2   (At read-only here)
      #pragma unroll
      for (int q = 0; q < 4; ++q) {
        int n = wcn + (q << 4) + l16;
        float bn = b2[n];
        #pragma unroll
        for (int r = 0; r < 4; ++r) {
          int m = wr16 + g4 + r;
          int row = r0 + m;
          float nv = (row < NN) ? nodes[(size_t)row * 256 + n] : 0.f;
          acc[q][r] = nv + bf2f(*(const u16*)AT_ADDR(m, n)) + acc[q][r] + bn;
        }
      }
    }
  }

  // ---- final LayerNorm ----
  LN_STATS();
  #pragma unroll
  for (int q = 0; q < 4; ++q) {
    int n = wcn + (q << 4) + l16;
    float scl = lnOs[n], bia = lnOb[n];
    #pragma unroll
    for (int r = 0; r < 4; ++r) {
      int m = wr16 + g4 + r;
      int row = r0 + m;
      if (row < NN)
        out[(size_t)row * 256 + n] =
            (acc[q][r] - murs[m][0]) * murs[m][1] * scl + bia;
    }
  }
}

// ---------------------------------------------------------------------------
extern "C" void kernel_launch(void* const* d_in, const int* in_sizes, int n_in,
                              void* d_out, int out_size, void* d_ws, size_t ws_size,
                              hipStream_t stream)
{
  const float* nodes = (const float*)d_in[0];
  const float* edges = (const float*)d_in[1];
  const int* senders = (const int*)d_in[2];
  const int* receivers = (const int*)d_in[3];
  const float* Wmsg = (const float*)d_in[4];
  const float* W0 = (const float*)d_in[5];
  const float* b0 = (const float*)d_in[6];
  const float* W1 = (const float*)d_in[7];
  const float* b1 = (const float*)d_in[8];
  const float* W2 = (const float*)d_in[9];
  const float* b2 = (const float*)d_in[10];
  const float* lnAs = (const float*)d_in[11];
  const float* lnAb = (const float*)d_in[12];
  const float* lnOs = (const float*)d_in[13];
  const float* lnOb = (const float*)d_in[14];
  float* out = (float*)d_out;
  (void)in_sizes; (void)n_in; (void)out_size; (void)ws_size;

  char* w = (char*)d_ws;
  size_t off = 0;
  auto take = [&](size_t b) { void* p = w + off; off += (b + 511) & ~(size_t)511; return p; };

  u16*   nodes_bf = (u16*)take((size_t)NN * 256 * 2);
  u16*   wmsg_p   = (u16*)take(320 * 256 * 2);
  u16*   w0_p     = (u16*)take(256 * 256 * 2);
  u16*   w1_p     = (u16*)take(256 * 256 * 2);
  u16*   w2_p     = (u16*)take(256 * 256 * 2);
  u16*   X        = (u16*)take((size_t)NN * 320 * 2);
  int*   cnt      = (int*)take((size_t)NN * 4);
  int*   loc      = (int*)take((size_t)NN * 4);
  int*   offs     = (int*)take((size_t)(NN + 1) * 4);
  int*   cursor   = (int*)take((size_t)NN * 4);
  int*   s_snd    = (int*)take((size_t)NE * 4);
  int*   s_eid    = (int*)take((size_t)NE * 4);
  int*   bsum     = (int*)take(256 * 4);
  int*   bpre     = (int*)take(256 * 4);

  const int NB = (NN + 255) / 256;  // 196

  hipMemsetAsync(cnt, 0, (size_t)NN * 4, stream);
  k_cvt<<<(NN * 256 / 4 + 255) / 256, 256, 0, stream>>>(nodes, nodes_bf, NN * 256 / 4);
  k_pack4<<<(320 * 256 + 3 * 256 * 256) / 256, 256, 0, stream>>>(
      Wmsg, W0, W1, W2, wmsg_p, w0_p, w1_p, w2_p);

  k_hist<<<(NE + 255) / 256, 256, 0, stream>>>(receivers, cnt);
  k_scan1<<<NB, 256, 0, stream>>>(cnt, loc, bsum);
  k_scan2<<<1, 256, 0, stream>>>(bsum, bpre, NB);
  k_scan3<<<NB, 256, 0, stream>>>(loc, bpre, offs, cursor);
  k_scatter<<<(NE + 255) / 256, 256, 0, stream>>>(senders, receivers, cursor, s_snd, s_eid);

  k_aggr<<<NN / 4, 256, 0, stream>>>(nodes_bf, edges, offs, s_snd, s_eid, X);

  const int MB = (NN + 63) / 64;    // 782
  k_fused<<<MB, 1024, 0, stream>>>(X, nodes, wmsg_p, w0_p, w1_p, w2_p,
                                   b0, b1, b2, lnAs, lnAb, lnOs, lnOb, out);
}